// Round 9
// baseline (281.217 us; speedup 1.0000x reference)
//
#include <hip/hip_runtime.h>
#include <hip/hip_bf16.h>
#include <stdint.h>

// Problem constants (from reference)
#define IN_F   1024
#define OUT_F  1024
#define NLEAF  16
#define BATCH  4096

// GEMM C'[n, b] = sum_i W'[n,i] * Xb[b,i],  n = o*16+l  (n = C-tile ROW dim).
// R14 = R12 resubmitted verbatim, third attempt (R12/R13 benches died on
// container acquisition — no compile/correctness/perf signal produced; hang
// audit clean: all waits satisfiable, barrier counts uniform, bounds OK).
// Rationale recap:
//   - R7/R9/R10/R11 all ~131us, MfmaUtil 44-48; measured cyc/K-tile =
//     MFMA floor + LDS-read floor (no overlap; cross-wave stagger defeated
//     by LDS round-robin arbitration under barrier-locked waves).
//   - 4 waves x 128x128 wave-tile (1 wave/SIMD): LDS reads 128KB/K-64
//     (was 192KB: A reread 4x -> 2x, B 2x -> 2x).
//   - mfma_f32_32x32x16_bf16: 4061 vs 3377 FLOP/cyc (m119) -> floor 2065
//     cyc/K-64; LDS 1536 now fits UNDER the MFMA window.
//   - overlap is within-wave ILP: frags double-buffered in regs, next-tile
//     prefetch streams across the (single) per-K-tile barrier; compiler
//     emits fine-grained lgkmcnt (m97: near-optimal).
//   - ring-4 x 32KB (BK=32), stage kt+3 during kt, boundary vmcnt(8)
//     proves kt+1 AND kt+2 landed -> prefetch of kt+1 frags race-free.
// Swizzle (64B rows): sigma=(row>>1)&3; stage slot=(c&3)^((c>>3)&3); read
// byte=((2*ks+h)^sigma)*16 -> returns k-octet 2*ks+h exactly; full 32-bank
// spread per 8 rows (2-way wave alias = free, m136).
#define KK      1024              // GEMM K = IN_F
#define NN      (OUT_F * NLEAF)   // 16384
#define BM      256               // n-tile
#define BN      256               // b-tile
#define BK      32
#define NKT     (KK / BK)         // 32 K-tiles
#define BUFB    32768             // ring buffer: A 16KB + B 16KB
#define GS_PAD  257               // g-tile LDS row stride

typedef __bf16 bf16x8 __attribute__((ext_vector_type(8)));
typedef float  f32x16 __attribute__((ext_vector_type(16)));

#define ASYNC_COPY16(gp, lp)                                                         \
  __builtin_amdgcn_global_load_lds((const __attribute__((address_space(1))) void*)(gp), \
                                   (__attribute__((address_space(3))) void*)(lp),       \
                                   16, 0, 0)

#define VM8  asm volatile("s_waitcnt vmcnt(8)" ::: "memory")
#define VM0  asm volatile("s_waitcnt vmcnt(0)" ::: "memory")
#define NOVM ((void)0)

// ---------------------------------------------------------------------------
// Kernel 1: fused prep.  Blocks [0,1024): transpose/pack pw -> W'.
// Blocks [1024,2048): gating softmax + x->bf16 pack (4 batch rows/block).
// ---------------------------------------------------------------------------
__global__ __launch_bounds__(256) void prep_kernel(
    const float* __restrict__ x, const float* __restrict__ gw,
    const float* __restrict__ gb, const float* __restrict__ pw,
    float* __restrict__ g, __hip_bfloat16* __restrict__ xb,
    __hip_bfloat16* __restrict__ W) {
  __shared__ __align__(16) __hip_bfloat16 lt[16 * 264];
  const int t = threadIdx.x;

  if (blockIdx.x < OUT_F) {
    // ---- pack_w path: W'[o*16+l, i] = bf16(pw[o,i,l]) via LDS transpose ----
    const int o = blockIdx.x;
    const float* src = pw + (size_t)o * (IN_F * NLEAF);
    for (int ch = 0; ch < 4; ++ch) {
      const float4* p = (const float4*)(src + ch * 4096 + t * 16);  // i=t, 16 l
      const float4 v0 = p[0], v1 = p[1], v2 = p[2], v3 = p[3];
      if (ch) __syncthreads();   // prev readout done before overwriting lt
      lt[ 0 * 264 + t] = __float2bfloat16(v0.x);
      lt[ 1 * 264 + t] = __float2bfloat16(v0.y);
      lt[ 2 * 264 + t] = __float2bfloat16(v0.z);
      lt[ 3 * 264 + t] = __float2bfloat16(v0.w);
      lt[ 4 * 264 + t] = __float2bfloat16(v1.x);
      lt[ 5 * 264 + t] = __float2bfloat16(v1.y);
      lt[ 6 * 264 + t] = __float2bfloat16(v1.z);
      lt[ 7 * 264 + t] = __float2bfloat16(v1.w);
      lt[ 8 * 264 + t] = __float2bfloat16(v2.x);
      lt[ 9 * 264 + t] = __float2bfloat16(v2.y);
      lt[10 * 264 + t] = __float2bfloat16(v2.z);
      lt[11 * 264 + t] = __float2bfloat16(v2.w);
      lt[12 * 264 + t] = __float2bfloat16(v3.x);
      lt[13 * 264 + t] = __float2bfloat16(v3.y);
      lt[14 * 264 + t] = __float2bfloat16(v3.z);
      lt[15 * 264 + t] = __float2bfloat16(v3.w);
      __syncthreads();
#pragma unroll
      for (int jj = 0; jj < 2; ++jj) {
        const int u = t + 256 * jj;        // 512 uint4 per chunk
        const int l = u >> 5;
        const int i8 = (u & 31) * 8;
        *(uint4*)(W + ((size_t)o * NLEAF + l) * KK + ch * 256 + i8) =
            *(const uint4*)(lt + l * 264 + i8);
      }
    }
  } else {
    // ---- gate + pack_x path ----
    const int blk  = blockIdx.x - OUT_F;
    const int lane = t & 63;
    const int wv   = t >> 6;
    const int b    = blk * 4 + wv;
    const int i4   = lane >> 4;
    const int l    = lane & 15;

    const float* xrow = x + (size_t)b * IN_F;
    float acc = 0.f;
#pragma unroll 8
    for (int k = 0; k < IN_F / 4; ++k) {
      const float xv = xrow[k * 4 + i4];          // same addr per 16-group (L1)
      const float wvv = gw[k * 64 + lane];        // coalesced
      acc = fmaf(xv, wvv, acc);
    }
    acc += __shfl_xor(acc, 16);
    acc += __shfl_xor(acc, 32);
    float logit = acc + gb[l];
    float m = logit;
#pragma unroll
    for (int off = 8; off > 0; off >>= 1) m = fmaxf(m, __shfl_xor(m, off));
    float e = __expf(logit - m);
    float s = e;
#pragma unroll
    for (int off = 8; off > 0; off >>= 1) s += __shfl_xor(s, off);
    if (lane < NLEAF) g[b * NLEAF + l] = e / s;

    const float* xblk = x + (size_t)blk * 4 * IN_F;
    __hip_bfloat16* xbblk = xb + (size_t)blk * 4 * IN_F;
#pragma unroll
    for (int j = 0; j < 2; ++j) {
      const int f = (t + 256 * j) * 8;
      const float4 a0 = *(const float4*)(xblk + f);
      const float4 a1 = *(const float4*)(xblk + f + 4);
      __align__(16) __hip_bfloat16 tmp[8];
      tmp[0] = __float2bfloat16(a0.x); tmp[1] = __float2bfloat16(a0.y);
      tmp[2] = __float2bfloat16(a0.z); tmp[3] = __float2bfloat16(a0.w);
      tmp[4] = __float2bfloat16(a1.x); tmp[5] = __float2bfloat16(a1.y);
      tmp[6] = __float2bfloat16(a1.z); tmp[7] = __float2bfloat16(a1.w);
      *(uint4*)(xbblk + f) = *(const uint4*)tmp;
    }
  }
}

// ---------------------------------------------------------------------------
// Kernel 2: bf16 MFMA GEMM, 256x256 tile, 4 waves x 128x128, 32x32x16 MFMA.
// Wave w: wr=w>>1 (A rows wr*128), wc=w&1 (B rows wc*128).
// acc[bi][bj] (f32x16) = 32x32 block at rows n0+wr*128+bi*32, cols
// b0+wc*128+bj*32.  C/D layout (verified m74/m101): col=lane&31,
// row=(reg&3)+8*(reg>>2)+4*(lane>>5).  A/B frag: row/col=lane&31,
// k=(lane>>5)*8+e (by analogy with the verified 16x16x32 mapping).
// ---------------------------------------------------------------------------
#define STAGE(ktt)                                                             \
  do {                                                                         \
    char* _b = smem + ((ktt) & 3) * BUFB;                                      \
    const __hip_bfloat16* _sa = aG + (long)(ktt) * BK;                         \
    const __hip_bfloat16* _sb = bG + (long)(ktt) * BK;                         \
    ASYNC_COPY16(_sa + gO,                _b + t * 16);                        \
    ASYNC_COPY16(_sa + gO +  64 * KK,     _b + t * 16 + 4096);                 \
    ASYNC_COPY16(_sa + gO + 128 * KK,     _b + t * 16 + 8192);                 \
    ASYNC_COPY16(_sa + gO + 192 * KK,     _b + t * 16 + 12288);                \
    ASYNC_COPY16(_sb + gO,                _b + 16384 + t * 16);                \
    ASYNC_COPY16(_sb + gO +  64 * KK,     _b + 16384 + t * 16 + 4096);         \
    ASYNC_COPY16(_sb + gO + 128 * KK,     _b + 16384 + t * 16 + 8192);         \
    ASYNC_COPY16(_sb + gO + 192 * KK,     _b + 16384 + t * 16 + 12288);        \
  } while (0)

#define RDA(D0, D1, D2, D3, U, KX)                                             \
  do {                                                                         \
    const char* _p = smem + (U) * BUFB + aRow + (KX);                          \
    D0 = *(const bf16x8*)(_p);                                                 \
    D1 = *(const bf16x8*)(_p + 2048);                                          \
    D2 = *(const bf16x8*)(_p + 4096);                                          \
    D3 = *(const bf16x8*)(_p + 6144);                                          \
  } while (0)

#define RDB(D0, D1, D2, D3, U, KX)                                             \
  do {                                                                         \
    const char* _p = smem + (U) * BUFB + bRow + (KX);                          \
    D0 = *(const bf16x8*)(_p);                                                 \
    D1 = *(const bf16x8*)(_p + 2048);                                          \
    D2 = *(const bf16x8*)(_p + 4096);                                          \
    D3 = *(const bf16x8*)(_p + 6144);                                          \
  } while (0)

#define MFMA16(A0, A1, A2, A3, B0, B1, B2, B3)                                 \
  acc[0][0] = __builtin_amdgcn_mfma_f32_32x32x16_bf16(A0, B0, acc[0][0], 0, 0, 0); \
  acc[0][1] = __builtin_amdgcn_mfma_f32_32x32x16_bf16(A0, B1, acc[0][1], 0, 0, 0); \
  acc[0][2] = __builtin_amdgcn_mfma_f32_32x32x16_bf16(A0, B2, acc[0][2], 0, 0, 0); \
  acc[0][3] = __builtin_amdgcn_mfma_f32_32x32x16_bf16(A0, B3, acc[0][3], 0, 0, 0); \
  acc[1][0] = __builtin_amdgcn_mfma_f32_32x32x16_bf16(A1, B0, acc[1][0], 0, 0, 0); \
  acc[1][1] = __builtin_amdgcn_mfma_f32_32x32x16_bf16(A1, B1, acc[1][1], 0, 0, 0); \
  acc[1][2] = __builtin_amdgcn_mfma_f32_32x32x16_bf16(A1, B2, acc[1][2], 0, 0, 0); \
  acc[1][3] = __builtin_amdgcn_mfma_f32_32x32x16_bf16(A1, B3, acc[1][3], 0, 0, 0); \
  acc[2][0] = __builtin_amdgcn_mfma_f32_32x32x16_bf16(A2, B0, acc[2][0], 0, 0, 0); \
  acc[2][1] = __builtin_amdgcn_mfma_f32_32x32x16_bf16(A2, B1, acc[2][1], 0, 0, 0); \
  acc[2][2] = __builtin_amdgcn_mfma_f32_32x32x16_bf16(A2, B2, acc[2][2], 0, 0, 0); \
  acc[2][3] = __builtin_amdgcn_mfma_f32_32x32x16_bf16(A2, B3, acc[2][3], 0, 0, 0); \
  acc[3][0] = __builtin_amdgcn_mfma_f32_32x32x16_bf16(A3, B0, acc[3][0], 0, 0, 0); \
  acc[3][1] = __builtin_amdgcn_mfma_f32_32x32x16_bf16(A3, B1, acc[3][1], 0, 0, 0); \
  acc[3][2] = __builtin_amdgcn_mfma_f32_32x32x16_bf16(A3, B2, acc[3][2], 0, 0, 0); \
  acc[3][3] = __builtin_amdgcn_mfma_f32_32x32x16_bf16(A3, B3, acc[3][3], 0, 0, 0);

// One K-tile (BK=32 = 2 k-steps of K=16).  On entry a*/b* hold ks0 frags of
// tile kt (prefetched during kt-1).  ks1 frags -> p/q; next tile's ks0 frags
// prefetched back into a/b during the ks1 MFMA window (register WAR keeps
// order; compiler interleaves ds_reads among MFMAs).
#define KTILE(kt, DOSTAGE, DOPRE, TAILVM, DOBAR)                               \
  do {                                                                         \
    if (DOSTAGE) STAGE((kt) + 3);                                              \
    RDA(p0, p1, p2, p3, (kt) & 3, kx1);                                        \
    RDB(q0, q1, q2, q3, (kt) & 3, kx1);                                        \
    MFMA16(a0, a1, a2, a3, b0, b1, b2, b3);                                    \
    if (DOPRE) {                                                               \
      RDA(a0, a1, a2, a3, ((kt) + 1) & 3, kx0);                                \
      RDB(b0, b1, b2, b3, ((kt) + 1) & 3, kx0);                                \
    }                                                                          \
    MFMA16(p0, p1, p2, p3, q0, q1, q2, q3);                                    \
    TAILVM;                                                                    \
    if (DOBAR) __builtin_amdgcn_s_barrier();                                   \
  } while (0)

__global__ __launch_bounds__(256, 1) void gemm_kernel(
    const __hip_bfloat16* __restrict__ Xb,  // [BATCH, KK]
    const __hip_bfloat16* __restrict__ W,   // [NN, KK], row n = o*16+l
    const float* __restrict__ g,            // [BATCH, NLEAF]
    const float* __restrict__ pb,           // [OUT_F, NLEAF]
    float* __restrict__ out) {              // [BATCH, OUT_F]
  extern __shared__ __align__(16) char smem[];  // 4 ring buffers x 32 KB

  const int t    = threadIdx.x;
  const int lane = t & 63;
  const int w    = t >> 6;    // 0..3
  const int r32  = lane & 31;
  const int h    = lane >> 5; // k-octet half
  const int wr   = w >> 1;    // A row-half
  const int wc   = w & 1;     // B row-half

  const int b0_ = blockIdx.x * BN;
  const int n0  = blockIdx.y * BM;

  const __hip_bfloat16* aG = W  + (long)n0 * KK;
  const __hip_bfloat16* bG = Xb + (long)b0_ * KK;

  // staging: chunk c = t + 256j; row = c>>2; LDS slot c&3 holds global
  // k-octet (c&3)^((c>>3)&3)  (slot is j-invariant: 64-row strides ≡ 0 mod 4
  // in (row>>1)&3)
  const long gO = (long)(t >> 2) * KK + (long)(((t & 3) ^ ((t >> 3) & 3)) * 8);

  // fragment reads: row r -> swizzled slot (2*ks+h)^((r>>1)&3)
  const int sw  = (r32 >> 1) & 3;
  const int kx0 = ((0 + h) ^ sw) * 16;
  const int kx1 = ((2 + h) ^ sw) * 16;
  const int aRow = (wr * 128 + r32) * 64;          // byte offset in A region
  const int bRow = 16384 + (wc * 128 + r32) * 64;  // byte offset in B region

  f32x16 acc[4][4] = {};
  bf16x8 a0, a1, a2, a3, b0, b1, b2, b3;
  bf16x8 p0, p1, p2, p3, q0, q1, q2, q3;

  // Prologue: stage tiles 0..2; vmcnt(8) lands tiles 0,1 (tile 2 in flight);
  // barrier publishes; preload tile-0 ks0 frags.
  STAGE(0); STAGE(1); STAGE(2);
  VM8;
  __builtin_amdgcn_s_barrier();
  RDA(a0, a1, a2, a3, 0, kx0);
  RDB(b0, b1, b2, b3, 0, kx0);

  // Steady state: stage kt+3 during kt; boundary vmcnt(8) leaves only
  // kt+3's 8 loads in flight -> kt+1 AND kt+2 proven landed, so the
  // next-tile prefetch (buffer kt+1) during kt is race-free.
  for (int kt = 0; kt < NKT - 4; kt += 4) {
    KTILE(kt + 0, 1, 1, VM8, 1);
    KTILE(kt + 1, 1, 1, VM8, 1);
    KTILE(kt + 2, 1, 1, VM8, 1);
    KTILE(kt + 3, 1, 1, VM8, 1);
  }
  KTILE(NKT - 4, 1, 1, VM8, 1);   // 28: stages 31
  KTILE(NKT - 3, 0, 1, VM0, 1);   // 29: drain -> tile 31 landed
  KTILE(NKT - 2, 0, 1, NOVM, 0);  // 30
  KTILE(NKT - 1, 0, 0, NOVM, 0);  // 31

  // ---- stage g (transposed, padded) and pb into the (dead) ring LDS ----
  __syncthreads();                                 // all frag reads done
  float* gs  = (float*)smem;                       // [16][GS_PAD]
  float* pbs = (float*)(smem + 16 * GS_PAD * 4);   // [256]
#pragma unroll
  for (int j = 0; j < 16; ++j) {
    const int f = t + 256 * j;                     // 0..4095
    gs[(f & 15) * GS_PAD + (f >> 4)] = g[b0_ * NLEAF + f];
  }
  pbs[t] = pb[(n0 >> 4) * NLEAF + t];              // 256 entries = 16 o x 16 l
  __syncthreads();

  // ---- fused gated-reduction epilogue (32x32 C/D layout) ----
  // lane holds cols cl=lane&31; reg r in 0..7 -> o_off 0, r in 8..15 -> o_off
  // 1; l(r) = (r&3) + 8*((r>>2)&1) + 4*h (same for r and r+8).  Lane pair
  // (h=0, h=1) covers complementary l-sets -> shfl_xor(32) completes sum_l.
  const int oBase = (n0 >> 4) + wr * 8;
#pragma unroll
  for (int bj = 0; bj < 4; ++bj) {
    const int bl = wc * 128 + bj * 32 + r32;       // local b-col
    float gv[8];
#pragma unroll
    for (int j = 0; j < 8; ++j)
      gv[j] = gs[((j & 3) + 8 * ((j >> 2) & 1) + 4 * h) * GS_PAD + bl];
#pragma unroll
    for (int bi = 0; bi < 4; ++bi) {
      const int o0 = wr * 8 + bi * 2;              // local o (even)
      float v0 = 0.f, v1 = 0.f;
#pragma unroll
      for (int j = 0; j < 8; ++j) {
        const int l = (j & 3) + 8 * ((j >> 2) & 1) + 4 * h;
        v0 = fmaf(acc[bi][bj][j]     + pbs[o0 * NLEAF + l],       gv[j], v0);
        v1 = fmaf(acc[bi][bj][j + 8] + pbs[(o0 + 1) * NLEAF + l], gv[j], v1);
      }
      v0 += __shfl_xor(v0, 32);
      v1 += __shfl_xor(v1, 32);
      if (h == 0)
        *(float2*)(out + (long)(b0_ + bl) * OUT_F + oBase + bi * 2) =
            make_float2(v0, v1);
    }
  }
}

// ---------------------------------------------------------------------------
// Fallback (ws too small for packed buffers): slow but correct fp32 path.
// ---------------------------------------------------------------------------
__global__ __launch_bounds__(256) void gate_kernel_fb(
    const float* __restrict__ x, const float* __restrict__ gw,
    const float* __restrict__ gb, float* __restrict__ g) {
  const int lane = threadIdx.x & 63;
  const int wv   = threadIdx.x >> 6;
  const int b    = blockIdx.x * 4 + wv;
  const int i4   = lane >> 4;
  const int l    = lane & 15;
  const float* xrow = x + (size_t)b * IN_F;
  float acc = 0.f;
  for (int k = 0; k < IN_F / 4; ++k)
    acc = fmaf(xrow[k * 4 + i4], gw[k * 64 + lane], acc);
  acc += __shfl_xor(acc, 16);
  acc += __shfl_xor(acc, 32);
  float logit = acc + gb[l];
  float m = logit;
  for (int off = 8; off > 0; off >>= 1) m = fmaxf(m, __shfl_xor(m, off));
  float e = __expf(logit - m);
  float s = e;
  for (int off = 8; off > 0; off >>= 1) s += __shfl_xor(s, off);
  if (lane < NLEAF) g[b * NLEAF + l] = e / s;
}

__global__ __launch_bounds__(256) void fallback_kernel(
    const float* __restrict__ x, const float* __restrict__ pw,
    const float* __restrict__ pb, const float* __restrict__ g,
    float* __restrict__ out) {
  const int b = blockIdx.x;
  __shared__ float xs[IN_F];
  __shared__ float gsl[NLEAF];
  const int t = threadIdx.x;
  for (int j = t; j < IN_F; j += 256) xs[j] = x[(long)b * IN_F + j];
  if (t < NLEAF) gsl[t] = g[b * NLEAF + t];
  __syncthreads();
  for (int o = t; o < OUT_F; o += 256) {
    const float* pwo = pw + (long)o * (IN_F * NLEAF);
    float acc = 0.f;
    for (int i = 0; i < IN_F; ++i) {
      const float xv = xs[i];
      float wsum = 0.f;
#pragma unroll
      for (int l = 0; l < NLEAF; ++l) wsum += gsl[l] * pwo[i * NLEAF + l];
      acc += xv * wsum;
    }
    float bias = 0.f;
#pragma unroll
    for (int l = 0; l < NLEAF; ++l) bias += gsl[l] * pb[o * NLEAF + l];
    out[(long)b * OUT_F + o] = acc + bias;
  }
}

extern "C" void kernel_launch(void* const* d_in, const int* in_sizes, int n_in,
                              void* d_out, int out_size, void* d_ws, size_t ws_size,
                              hipStream_t stream) {
  const float* x  = (const float*)d_in[0];  // [4096,1024]
  const float* gw = (const float*)d_in[1];  // [1024,16]
  const float* gb = (const float*)d_in[2];  // [16]
  const float* pw = (const float*)d_in[3];  // [1024,1024,16]
  const float* pb = (const float*)d_in[4];  // [1024,16]
  float* out = (float*)d_out;               // [4096,1024]

  const size_t w_bytes  = (size_t)NN * KK * sizeof(__hip_bfloat16);    // 33.6 MB
  const size_t xb_bytes = (size_t)BATCH * KK * sizeof(__hip_bfloat16); //  8.4 MB
  const size_t g_bytes  = (size_t)BATCH * NLEAF * sizeof(float);       //  0.26 MB

  if (ws_size >= w_bytes + xb_bytes + g_bytes) {
    __hip_bfloat16* W  = (__hip_bfloat16*)d_ws;
    __hip_bfloat16* xb = (__hip_bfloat16*)((char*)d_ws + w_bytes);
    float*          g  = (float*)((char*)d_ws + w_bytes + xb_bytes);

    static int attr_done = 0;
    if (!attr_done) {
      // 128 KB dynamic LDS (> 64 KB default cap); gfx950 has 160 KB/CU.
      (void)hipFuncSetAttribute((const void*)gemm_kernel,
                                hipFuncAttributeMaxDynamicSharedMemorySize,
                                131072);
      attr_done = 1;
    }

    prep_kernel<<<OUT_F + BATCH / 4, 256, 0, stream>>>(x, gw, gb, pw, g, xb, W);
    gemm_kernel<<<dim3(BATCH / BN, NN / BM), 256, 131072, stream>>>(
        xb, W, g, pb, out);
  } else {
    float* g = (float*)d_ws;  // needs only 256 KB
    gate_kernel_fb<<<BATCH / 4, 256, 0, stream>>>(x, gw, gb, g);
    fallback_kernel<<<BATCH, 256, 0, stream>>>(x, pw, pb, g, out);
  }
}

// Round 10
// 277.307 us; speedup vs baseline: 1.0141x; 1.0141x over previous
//
#include <hip/hip_runtime.h>
#include <hip/hip_bf16.h>
#include <stdint.h>

// Problem constants (from reference)
#define IN_F   1024
#define OUT_F  1024
#define NLEAF  16
#define BATCH  4096

// GEMM C'[n, b] = sum_i W'[n,i] * Xb[b,i],  n = o*16+l  (n = C-tile ROW dim).
// R15 = R12 with the LDS swizzle fixed.  R12's run PASSED correctness
// (32x32x16 operand mapping + epilogue verified) but regressed to 150.9us
// with SQ_LDS_BANK_CONFLICT 393K -> 8.5M: 64-B rows give the swizzle only
// 4 slot positions -> 4-way read conflicts.  Fix: pair-row 128-B macro-row
// swizzle: byte(m= r>>1, r&1, s) = m*128 + p*16, p = ((r&1)*4+s) ^ (m&7).
// Per ds_read_b128 the 64 lanes now spread uniformly 8 lanes/8 positions =
// the b128 minimum (same structure as R11's measured-conflict-free scheme).
// Staging stays linear-dest gload_lds with pre-swizzled GLOBAL source:
// chunk c -> q=(c&7)^((c>>3)&7), global row = 2*(c>>3)+(q>>2), octet q&3.
// Everything else (4 waves x 128x128, 32x32x16 MFMA, ring-4 BK=32,
// stage kt+3 / vmcnt(8), reg double-buffer, fused epilogue) unchanged.
#define KK      1024              // GEMM K = IN_F
#define NN      (OUT_F * NLEAF)   // 16384
#define BM      256               // n-tile
#define BN      256               // b-tile
#define BK      32
#define NKT     (KK / BK)         // 32 K-tiles
#define BUFB    32768             // ring buffer: A 16KB + B 16KB
#define GS_PAD  257               // g-tile LDS row stride

typedef __bf16 bf16x8 __attribute__((ext_vector_type(8)));
typedef float  f32x16 __attribute__((ext_vector_type(16)));

#define ASYNC_COPY16(gp, lp)                                                         \
  __builtin_amdgcn_global_load_lds((const __attribute__((address_space(1))) void*)(gp), \
                                   (__attribute__((address_space(3))) void*)(lp),       \
                                   16, 0, 0)

#define VM8  asm volatile("s_waitcnt vmcnt(8)" ::: "memory")
#define VM0  asm volatile("s_waitcnt vmcnt(0)" ::: "memory")
#define NOVM ((void)0)

// ---------------------------------------------------------------------------
// Kernel 1: fused prep.  Blocks [0,1024): transpose/pack pw -> W'.
// Blocks [1024,2048): gating softmax + x->bf16 pack (4 batch rows/block).
// ---------------------------------------------------------------------------
__global__ __launch_bounds__(256) void prep_kernel(
    const float* __restrict__ x, const float* __restrict__ gw,
    const float* __restrict__ gb, const float* __restrict__ pw,
    float* __restrict__ g, __hip_bfloat16* __restrict__ xb,
    __hip_bfloat16* __restrict__ W) {
  __shared__ __align__(16) __hip_bfloat16 lt[16 * 264];
  const int t = threadIdx.x;

  if (blockIdx.x < OUT_F) {
    // ---- pack_w path: W'[o*16+l, i] = bf16(pw[o,i,l]) via LDS transpose ----
    const int o = blockIdx.x;
    const float* src = pw + (size_t)o * (IN_F * NLEAF);
    for (int ch = 0; ch < 4; ++ch) {
      const float4* p = (const float4*)(src + ch * 4096 + t * 16);  // i=t, 16 l
      const float4 v0 = p[0], v1 = p[1], v2 = p[2], v3 = p[3];
      if (ch) __syncthreads();   // prev readout done before overwriting lt
      lt[ 0 * 264 + t] = __float2bfloat16(v0.x);
      lt[ 1 * 264 + t] = __float2bfloat16(v0.y);
      lt[ 2 * 264 + t] = __float2bfloat16(v0.z);
      lt[ 3 * 264 + t] = __float2bfloat16(v0.w);
      lt[ 4 * 264 + t] = __float2bfloat16(v1.x);
      lt[ 5 * 264 + t] = __float2bfloat16(v1.y);
      lt[ 6 * 264 + t] = __float2bfloat16(v1.z);
      lt[ 7 * 264 + t] = __float2bfloat16(v1.w);
      lt[ 8 * 264 + t] = __float2bfloat16(v2.x);
      lt[ 9 * 264 + t] = __float2bfloat16(v2.y);
      lt[10 * 264 + t] = __float2bfloat16(v2.z);
      lt[11 * 264 + t] = __float2bfloat16(v2.w);
      lt[12 * 264 + t] = __float2bfloat16(v3.x);
      lt[13 * 264 + t] = __float2bfloat16(v3.y);
      lt[14 * 264 + t] = __float2bfloat16(v3.z);
      lt[15 * 264 + t] = __float2bfloat16(v3.w);
      __syncthreads();
#pragma unroll
      for (int jj = 0; jj < 2; ++jj) {
        const int u = t + 256 * jj;        // 512 uint4 per chunk
        const int l = u >> 5;
        const int i8 = (u & 31) * 8;
        *(uint4*)(W + ((size_t)o * NLEAF + l) * KK + ch * 256 + i8) =
            *(const uint4*)(lt + l * 264 + i8);
      }
    }
  } else {
    // ---- gate + pack_x path ----
    const int blk  = blockIdx.x - OUT_F;
    const int lane = t & 63;
    const int wv   = t >> 6;
    const int b    = blk * 4 + wv;
    const int i4   = lane >> 4;
    const int l    = lane & 15;

    const float* xrow = x + (size_t)b * IN_F;
    float acc = 0.f;
#pragma unroll 8
    for (int k = 0; k < IN_F / 4; ++k) {
      const float xv = xrow[k * 4 + i4];          // same addr per 16-group (L1)
      const float wvv = gw[k * 64 + lane];        // coalesced
      acc = fmaf(xv, wvv, acc);
    }
    acc += __shfl_xor(acc, 16);
    acc += __shfl_xor(acc, 32);
    float logit = acc + gb[l];
    float m = logit;
#pragma unroll
    for (int off = 8; off > 0; off >>= 1) m = fmaxf(m, __shfl_xor(m, off));
    float e = __expf(logit - m);
    float s = e;
#pragma unroll
    for (int off = 8; off > 0; off >>= 1) s += __shfl_xor(s, off);
    if (lane < NLEAF) g[b * NLEAF + l] = e / s;

    const float* xblk = x + (size_t)blk * 4 * IN_F;
    __hip_bfloat16* xbblk = xb + (size_t)blk * 4 * IN_F;
#pragma unroll
    for (int j = 0; j < 2; ++j) {
      const int f = (t + 256 * j) * 8;
      const float4 a0 = *(const float4*)(xblk + f);
      const float4 a1 = *(const float4*)(xblk + f + 4);
      __align__(16) __hip_bfloat16 tmp[8];
      tmp[0] = __float2bfloat16(a0.x); tmp[1] = __float2bfloat16(a0.y);
      tmp[2] = __float2bfloat16(a0.z); tmp[3] = __float2bfloat16(a0.w);
      tmp[4] = __float2bfloat16(a1.x); tmp[5] = __float2bfloat16(a1.y);
      tmp[6] = __float2bfloat16(a1.z); tmp[7] = __float2bfloat16(a1.w);
      *(uint4*)(xbblk + f) = *(const uint4*)tmp;
    }
  }
}

// ---------------------------------------------------------------------------
// Kernel 2: bf16 MFMA GEMM, 256x256 tile, 4 waves x 128x128, 32x32x16 MFMA.
// Wave w: wr=w>>1 (A rows wr*128), wc=w&1 (B rows wc*128).
// acc[bi][bj] (f32x16) = 32x32 block at rows n0+wr*128+bi*32, cols
// b0+wc*128+bj*32.  C/D layout (verified m74/m101 + R12 absmax pass):
// col=lane&31, row=(reg&3)+8*(reg>>2)+4*(lane>>5).  A/B frag: row=lane&31,
// k=(lane>>5)*8+e (verified by R12 absmax pass).
// LDS layout (pair-row swizzle): macro-row m=r>>1 (128 B); 16-B unit p of m
// holds global (row 2m+(q>>2), k-octet q&3), q = p ^ (m&7).
// ---------------------------------------------------------------------------
#define STAGE(ktt)                                                             \
  do {                                                                         \
    char* _b = smem + ((ktt) & 3) * BUFB;                                      \
    const __hip_bfloat16* _sa = aG + (long)(ktt) * BK;                         \
    const __hip_bfloat16* _sb = bG + (long)(ktt) * BK;                         \
    ASYNC_COPY16(_sa + gO,                _b + t * 16);                        \
    ASYNC_COPY16(_sa + gO +  64 * KK,     _b + t * 16 + 4096);                 \
    ASYNC_COPY16(_sa + gO + 128 * KK,     _b + t * 16 + 8192);                 \
    ASYNC_COPY16(_sa + gO + 192 * KK,     _b + t * 16 + 12288);                \
    ASYNC_COPY16(_sb + gO,                _b + 16384 + t * 16);                \
    ASYNC_COPY16(_sb + gO +  64 * KK,     _b + 16384 + t * 16 + 4096);         \
    ASYNC_COPY16(_sb + gO + 128 * KK,     _b + 16384 + t * 16 + 8192);         \
    ASYNC_COPY16(_sb + gO + 192 * KK,     _b + 16384 + t * 16 + 12288);        \
  } while (0)

#define RDA(D0, D1, D2, D3, U, KX)                                             \
  do {                                                                         \
    const char* _p = smem + (U) * BUFB + aRow + (KX);                          \
    D0 = *(const bf16x8*)(_p);                                                 \
    D1 = *(const bf16x8*)(_p + 2048);                                          \
    D2 = *(const bf16x8*)(_p + 4096);                                          \
    D3 = *(const bf16x8*)(_p + 6144);                                          \
  } while (0)

#define RDB(D0, D1, D2, D3, U, KX)                                             \
  do {                                                                         \
    const char* _p = smem + (U) * BUFB + bRow + (KX);                          \
    D0 = *(const bf16x8*)(_p);                                                 \
    D1 = *(const bf16x8*)(_p + 2048);                                          \
    D2 = *(const bf16x8*)(_p + 4096);                                          \
    D3 = *(const bf16x8*)(_p + 6144);                                          \
  } while (0)

#define MFMA16(A0, A1, A2, A3, B0, B1, B2, B3)                                 \
  acc[0][0] = __builtin_amdgcn_mfma_f32_32x32x16_bf16(A0, B0, acc[0][0], 0, 0, 0); \
  acc[0][1] = __builtin_amdgcn_mfma_f32_32x32x16_bf16(A0, B1, acc[0][1], 0, 0, 0); \
  acc[0][2] = __builtin_amdgcn_mfma_f32_32x32x16_bf16(A0, B2, acc[0][2], 0, 0, 0); \
  acc[0][3] = __builtin_amdgcn_mfma_f32_32x32x16_bf16(A0, B3, acc[0][3], 0, 0, 0); \
  acc[1][0] = __builtin_amdgcn_mfma_f32_32x32x16_bf16(A1, B0, acc[1][0], 0, 0, 0); \
  acc[1][1] = __builtin_amdgcn_mfma_f32_32x32x16_bf16(A1, B1, acc[1][1], 0, 0, 0); \
  acc[1][2] = __builtin_amdgcn_mfma_f32_32x32x16_bf16(A1, B2, acc[1][2], 0, 0, 0); \
  acc[1][3] = __builtin_amdgcn_mfma_f32_32x32x16_bf16(A1, B3, acc[1][3], 0, 0, 0); \
  acc[2][0] = __builtin_amdgcn_mfma_f32_32x32x16_bf16(A2, B0, acc[2][0], 0, 0, 0); \
  acc[2][1] = __builtin_amdgcn_mfma_f32_32x32x16_bf16(A2, B1, acc[2][1], 0, 0, 0); \
  acc[2][2] = __builtin_amdgcn_mfma_f32_32x32x16_bf16(A2, B2, acc[2][2], 0, 0, 0); \
  acc[2][3] = __builtin_amdgcn_mfma_f32_32x32x16_bf16(A2, B3, acc[2][3], 0, 0, 0); \
  acc[3][0] = __builtin_amdgcn_mfma_f32_32x32x16_bf16(A3, B0, acc[3][0], 0, 0, 0); \
  acc[3][1] = __builtin_amdgcn_mfma_f32_32x32x16_bf16(A3, B1, acc[3][1], 0, 0, 0); \
  acc[3][2] = __builtin_amdgcn_mfma_f32_32x32x16_bf16(A3, B2, acc[3][2], 0, 0, 0); \
  acc[3][3] = __builtin_amdgcn_mfma_f32_32x32x16_bf16(A3, B3, acc[3][3], 0, 0, 0);

// One K-tile (BK=32 = 2 k-steps of K=16).  On entry a*/b* hold ks0 frags of
// tile kt (prefetched during kt-1).  ks1 frags -> p/q; next tile's ks0 frags
// prefetched back into a/b during the ks1 MFMA window (register WAR keeps
// order; compiler interleaves ds_reads among MFMAs).
#define KTILE(kt, DOSTAGE, DOPRE, TAILVM, DOBAR)                               \
  do {                                                                         \
    if (DOSTAGE) STAGE((kt) + 3);                                              \
    RDA(p0, p1, p2, p3, (kt) & 3, kx1);                                        \
    RDB(q0, q1, q2, q3, (kt) & 3, kx1);                                        \
    MFMA16(a0, a1, a2, a3, b0, b1, b2, b3);                                    \
    if (DOPRE) {                                                               \
      RDA(a0, a1, a2, a3, ((kt) + 1) & 3, kx0);                                \
      RDB(b0, b1, b2, b3, ((kt) + 1) & 3, kx0);                                \
    }                                                                          \
    MFMA16(p0, p1, p2, p3, q0, q1, q2, q3);                                    \
    TAILVM;                                                                    \
    if (DOBAR) __builtin_amdgcn_s_barrier();                                   \
  } while (0)

__global__ __launch_bounds__(256, 1) void gemm_kernel(
    const __hip_bfloat16* __restrict__ Xb,  // [BATCH, KK]
    const __hip_bfloat16* __restrict__ W,   // [NN, KK], row n = o*16+l
    const float* __restrict__ g,            // [BATCH, NLEAF]
    const float* __restrict__ pb,           // [OUT_F, NLEAF]
    float* __restrict__ out) {              // [BATCH, OUT_F]
  extern __shared__ __align__(16) char smem[];  // 4 ring buffers x 32 KB

  const int t    = threadIdx.x;
  const int lane = t & 63;
  const int w    = t >> 6;    // 0..3
  const int r32  = lane & 31;
  const int h    = lane >> 5; // k-octet half
  const int wr   = w >> 1;    // A row-half
  const int wc   = w & 1;     // B row-half

  const int b0_ = blockIdx.x * BN;
  const int n0  = blockIdx.y * BM;

  const __hip_bfloat16* aG = W  + (long)n0 * KK;
  const __hip_bfloat16* bG = Xb + (long)b0_ * KK;

  // staging source (pair-row swizzle): chunk c = t + 256*seg; macro-row
  // m = c>>3 (seg adds 32 -> m&7 j-invariant); q = (c&7)^(m&7);
  // global row = 2*m + (q>>2)  (seg adds 64 rows), k-octet = q&3.
  const int  q7 = (t & 7) ^ ((t >> 3) & 7);
  const long gO = (long)(2 * (t >> 3) + (q7 >> 2)) * KK + (long)((q7 & 3) * 8);

  // fragment reads: lane row r = (wr|wc)*128 + r32, macro-row m = base + r32>>1,
  // byte = m*128 + p*16, p = ((r32&1)*4 + 2*ks + h) ^ (m&7); m&7 = (r32>>1)&7.
  const int sw7   = (r32 >> 1) & 7;
  const int base4 = (r32 & 1) * 4 + h;
  const int kx0 = ((base4 + 0) ^ sw7) * 16;
  const int kx1 = ((base4 + 2) ^ sw7) * 16;
  const int aRow = (wr * 64 + (r32 >> 1)) * 128;           // A region byte base
  const int bRow = 16384 + (wc * 64 + (r32 >> 1)) * 128;   // B region byte base

  f32x16 acc[4][4] = {};
  bf16x8 a0, a1, a2, a3, b0, b1, b2, b3;
  bf16x8 p0, p1, p2, p3, q0, q1, q2, q3;

  // Prologue: stage tiles 0..2; vmcnt(8) lands tiles 0,1 (tile 2 in flight);
  // barrier publishes; preload tile-0 ks0 frags.
  STAGE(0); STAGE(1); STAGE(2);
  VM8;
  __builtin_amdgcn_s_barrier();
  RDA(a0, a1, a2, a3, 0, kx0);
  RDB(b0, b1, b2, b3, 0, kx0);

  // Steady state: stage kt+3 during kt; boundary vmcnt(8) leaves only
  // kt+3's 8 loads in flight -> kt+1 AND kt+2 proven landed, so the
  // next-tile prefetch (buffer kt+1) during kt is race-free.
  for (int kt = 0; kt < NKT - 4; kt += 4) {
    KTILE(kt + 0, 1, 1, VM8, 1);
    KTILE(kt + 1, 1, 1, VM8, 1);
    KTILE(kt + 2, 1, 1, VM8, 1);
    KTILE(kt + 3, 1, 1, VM8, 1);
  }
  KTILE(NKT - 4, 1, 1, VM8, 1);   // 28: stages 31
  KTILE(NKT - 3, 0, 1, VM0, 1);   // 29: drain -> tile 31 landed
  KTILE(NKT - 2, 0, 1, NOVM, 0);  // 30
  KTILE(NKT - 1, 0, 0, NOVM, 0);  // 31

  // ---- stage g (transposed, padded) and pb into the (dead) ring LDS ----
  __syncthreads();                                 // all frag reads done
  float* gs  = (float*)smem;                       // [16][GS_PAD]
  float* pbs = (float*)(smem + 16 * GS_PAD * 4);   // [256]
#pragma unroll
  for (int j = 0; j < 16; ++j) {
    const int f = t + 256 * j;                     // 0..4095
    gs[(f & 15) * GS_PAD + (f >> 4)] = g[b0_ * NLEAF + f];
  }
  pbs[t] = pb[(n0 >> 4) * NLEAF + t];              // 256 entries = 16 o x 16 l
  __syncthreads();

  // ---- fused gated-reduction epilogue (32x32 C/D layout) ----
  // lane holds cols cl=lane&31; reg r in 0..7 -> o_off 0, r in 8..15 -> o_off
  // 1; l(r) = (r&3) + 8*((r>>2)&1) + 4*h (same for r and r+8).  Lane pair
  // (h=0, h=1) covers complementary l-sets -> shfl_xor(32) completes sum_l.
  const int oBase = (n0 >> 4) + wr * 8;
#pragma unroll
  for (int bj = 0; bj < 4; ++bj) {
    const int bl = wc * 128 + bj * 32 + r32;       // local b-col
    float gv[8];
#pragma unroll
    for (int j = 0; j < 8; ++j)
      gv[j] = gs[((j & 3) + 8 * ((j >> 2) & 1) + 4 * h) * GS_PAD + bl];
#pragma unroll
    for (int bi = 0; bi < 4; ++bi) {
      const int o0 = wr * 8 + bi * 2;              // local o (even)
      float v0 = 0.f, v1 = 0.f;
#pragma unroll
      for (int j = 0; j < 8; ++j) {
        const int l = (j & 3) + 8 * ((j >> 2) & 1) + 4 * h;
        v0 = fmaf(acc[bi][bj][j]     + pbs[o0 * NLEAF + l],       gv[j], v0);
        v1 = fmaf(acc[bi][bj][j + 8] + pbs[(o0 + 1) * NLEAF + l], gv[j], v1);
      }
      v0 += __shfl_xor(v0, 32);
      v1 += __shfl_xor(v1, 32);
      if (h == 0)
        *(float2*)(out + (long)(b0_ + bl) * OUT_F + oBase + bi * 2) =
            make_float2(v0, v1);
    }
  }
}

// ---------------------------------------------------------------------------
// Fallback (ws too small for packed buffers): slow but correct fp32 path.
// ---------------------------------------------------------------------------
__global__ __launch_bounds__(256) void gate_kernel_fb(
    const float* __restrict__ x, const float* __restrict__ gw,
    const float* __restrict__ gb, float* __restrict__ g) {
  const int lane = threadIdx.x & 63;
  const int wv   = threadIdx.x >> 6;
  const int b    = blockIdx.x * 4 + wv;
  const int i4   = lane >> 4;
  const int l    = lane & 15;
  const float* xrow = x + (size_t)b * IN_F;
  float acc = 0.f;
  for (int k = 0; k < IN_F / 4; ++k)
    acc = fmaf(xrow[k * 4 + i4], gw[k * 64 + lane], acc);
  acc += __shfl_xor(acc, 16);
  acc += __shfl_xor(acc, 32);
  float logit = acc + gb[l];
  float m = logit;
  for (int off = 8; off > 0; off >>= 1) m = fmaxf(m, __shfl_xor(m, off));
  float e = __expf(logit - m);
  float s = e;
  for (int off = 8; off > 0; off >>= 1) s += __shfl_xor(s, off);
  if (lane < NLEAF) g[b * NLEAF + l] = e / s;
}

__global__ __launch_bounds__(256) void fallback_kernel(
    const float* __restrict__ x, const float* __restrict__ pw,
    const float* __restrict__ pb, const float* __restrict__ g,
    float* __restrict__ out) {
  const int b = blockIdx.x;
  __shared__ float xs[IN_F];
  __shared__ float gsl[NLEAF];
  const int t = threadIdx.x;
  for (int j = t; j < IN_F; j += 256) xs[j] = x[(long)b * IN_F + j];
  if (t < NLEAF) gsl[t] = g[b * NLEAF + t];
  __syncthreads();
  for (int o = t; o < OUT_F; o += 256) {
    const float* pwo = pw + (long)o * (IN_F * NLEAF);
    float acc = 0.f;
    for (int i = 0; i < IN_F; ++i) {
      const float xv = xs[i];
      float wsum = 0.f;
#pragma unroll
      for (int l = 0; l < NLEAF; ++l) wsum += gsl[l] * pwo[i * NLEAF + l];
      acc += xv * wsum;
    }
    float bias = 0.f;
#pragma unroll
    for (int l = 0; l < NLEAF; ++l) bias += gsl[l] * pb[o * NLEAF + l];
    out[(long)b * OUT_F + o] = acc + bias;
  }
}

extern "C" void kernel_launch(void* const* d_in, const int* in_sizes, int n_in,
                              void* d_out, int out_size, void* d_ws, size_t ws_size,
                              hipStream_t stream) {
  const float* x  = (const float*)d_in[0];  // [4096,1024]
  const float* gw = (const float*)d_in[1];  // [1024,16]
  const float* gb = (const float*)d_in[2];  // [16]
  const float* pw = (const float*)d_in[3];  // [1024,1024,16]
  const float* pb = (const float*)d_in[4];  // [1024,16]
  float* out = (float*)d_out;               // [4096,1024]

  const size_t w_bytes  = (size_t)NN * KK * sizeof(__hip_bfloat16);    // 33.6 MB
  const size_t xb_bytes = (size_t)BATCH * KK * sizeof(__hip_bfloat16); //  8.4 MB
  const size_t g_bytes  = (size_t)BATCH * NLEAF * sizeof(float);       //  0.26 MB

  if (ws_size >= w_bytes + xb_bytes + g_bytes) {
    __hip_bfloat16* W  = (__hip_bfloat16*)d_ws;
    __hip_bfloat16* xb = (__hip_bfloat16*)((char*)d_ws + w_bytes);
    float*          g  = (float*)((char*)d_ws + w_bytes + xb_bytes);

    static int attr_done = 0;
    if (!attr_done) {
      // 128 KB dynamic LDS (> 64 KB default cap); gfx950 has 160 KB/CU.
      (void)hipFuncSetAttribute((const void*)gemm_kernel,
                                hipFuncAttributeMaxDynamicSharedMemorySize,
                                131072);
      attr_done = 1;
    }

    prep_kernel<<<OUT_F + BATCH / 4, 256, 0, stream>>>(x, gw, gb, pw, g, xb, W);
    gemm_kernel<<<dim3(BATCH / BN, NN / BM), 256, 131072, stream>>>(
        xb, W, g, pb, out);
  } else {
    float* g = (float*)d_ws;  // needs only 256 KB
    gate_kernel_fb<<<BATCH / 4, 256, 0, stream>>>(x, gw, gb, g);
    fallback_kernel<<<BATCH, 256, 0, stream>>>(x, pw, pb, g, out);
  }
}

// Round 11
// 251.847 us; speedup vs baseline: 1.1166x; 1.1011x over previous
//
#include <hip/hip_runtime.h>
#include <hip/hip_bf16.h>
#include <stdint.h>

// Problem constants (from reference)
#define IN_F   1024
#define OUT_F  1024
#define NLEAF  16
#define BATCH  4096

// GEMM C'[n, b] = sum_i W'[n,i] * Xb[b,i],  n = o*16+l  (n = C-tile ROW dim).
// R16 = R11 (best measured gemm: 131.2us, conflicts 393K, total 249.1)
// restored verbatim + T1 XCD-chunked block swizzle (bijective, nwg=1024%8==0:
// swz=(lin&7)*128+(lin>>3) -> each XCD gets 8 contiguous A-panel rows = 4MB
// = its L2).  The 4-wave/32x32 family (R12/R15) is abandoned: two rounds,
// identical 8.5M conflicts under different swizzles (model wrong), MfmaUtil
// 40%, no TLP at 1 wave/SIMD.  8-wave 8-phase structure wins.
#define KK      1024              // GEMM K = IN_F
#define NN      (OUT_F * NLEAF)   // 16384
#define BM      256               // n-tile
#define BN      256               // b-tile
#define BK      64
#define NKT     (KK / BK)         // 16 K-tiles
#define GS_PAD  257               // g-tile LDS row stride (conflict-free quads)

typedef __bf16 bf16x8 __attribute__((ext_vector_type(8)));
typedef float  f32x4  __attribute__((ext_vector_type(4)));

#define ASYNC_COPY16(gp, lp)                                                         \
  __builtin_amdgcn_global_load_lds((const __attribute__((address_space(1))) void*)(gp), \
                                   (__attribute__((address_space(3))) void*)(lp),       \
                                   16, 0, 0)

// ---------------------------------------------------------------------------
// Kernel 1: fused prep.  Blocks [0,1024): transpose/pack pw -> W'.
// Blocks [1024,2048): gating softmax + x->bf16 pack (4 batch rows/block).
// ---------------------------------------------------------------------------
__global__ __launch_bounds__(256) void prep_kernel(
    const float* __restrict__ x, const float* __restrict__ gw,
    const float* __restrict__ gb, const float* __restrict__ pw,
    float* __restrict__ g, __hip_bfloat16* __restrict__ xb,
    __hip_bfloat16* __restrict__ W) {
  __shared__ __align__(16) __hip_bfloat16 lt[16 * 264];
  const int t = threadIdx.x;

  if (blockIdx.x < OUT_F) {
    // ---- pack_w path: W'[o*16+l, i] = bf16(pw[o,i,l]) via LDS transpose ----
    const int o = blockIdx.x;
    const float* src = pw + (size_t)o * (IN_F * NLEAF);
    for (int ch = 0; ch < 4; ++ch) {
      const float4* p = (const float4*)(src + ch * 4096 + t * 16);  // i=t, 16 l
      const float4 v0 = p[0], v1 = p[1], v2 = p[2], v3 = p[3];
      if (ch) __syncthreads();   // prev readout done before overwriting lt
      lt[ 0 * 264 + t] = __float2bfloat16(v0.x);
      lt[ 1 * 264 + t] = __float2bfloat16(v0.y);
      lt[ 2 * 264 + t] = __float2bfloat16(v0.z);
      lt[ 3 * 264 + t] = __float2bfloat16(v0.w);
      lt[ 4 * 264 + t] = __float2bfloat16(v1.x);
      lt[ 5 * 264 + t] = __float2bfloat16(v1.y);
      lt[ 6 * 264 + t] = __float2bfloat16(v1.z);
      lt[ 7 * 264 + t] = __float2bfloat16(v1.w);
      lt[ 8 * 264 + t] = __float2bfloat16(v2.x);
      lt[ 9 * 264 + t] = __float2bfloat16(v2.y);
      lt[10 * 264 + t] = __float2bfloat16(v2.z);
      lt[11 * 264 + t] = __float2bfloat16(v2.w);
      lt[12 * 264 + t] = __float2bfloat16(v3.x);
      lt[13 * 264 + t] = __float2bfloat16(v3.y);
      lt[14 * 264 + t] = __float2bfloat16(v3.z);
      lt[15 * 264 + t] = __float2bfloat16(v3.w);
      __syncthreads();
#pragma unroll
      for (int jj = 0; jj < 2; ++jj) {
        const int u = t + 256 * jj;        // 512 uint4 per chunk
        const int l = u >> 5;
        const int i8 = (u & 31) * 8;
        *(uint4*)(W + ((size_t)o * NLEAF + l) * KK + ch * 256 + i8) =
            *(const uint4*)(lt + l * 264 + i8);
      }
    }
  } else {
    // ---- gate + pack_x path ----
    const int blk  = blockIdx.x - OUT_F;
    const int lane = t & 63;
    const int wv   = t >> 6;
    const int b    = blk * 4 + wv;
    const int i4   = lane >> 4;
    const int l    = lane & 15;

    const float* xrow = x + (size_t)b * IN_F;
    float acc = 0.f;
#pragma unroll 8
    for (int k = 0; k < IN_F / 4; ++k) {
      const float xv = xrow[k * 4 + i4];          // same addr per 16-group (L1)
      const float wvv = gw[k * 64 + lane];        // coalesced
      acc = fmaf(xv, wvv, acc);
    }
    acc += __shfl_xor(acc, 16);
    acc += __shfl_xor(acc, 32);
    float logit = acc + gb[l];
    float m = logit;
#pragma unroll
    for (int off = 8; off > 0; off >>= 1) m = fmaxf(m, __shfl_xor(m, off));
    float e = __expf(logit - m);
    float s = e;
#pragma unroll
    for (int off = 8; off > 0; off >>= 1) s += __shfl_xor(s, off);
    if (lane < NLEAF) g[b * NLEAF + l] = e / s;

    const float* xblk = x + (size_t)blk * 4 * IN_F;
    __hip_bfloat16* xbblk = xb + (size_t)blk * 4 * IN_F;
#pragma unroll
    for (int j = 0; j < 2; ++j) {
      const int f = (t + 256 * j) * 8;
      const float4 a0 = *(const float4*)(xblk + f);
      const float4 a1 = *(const float4*)(xblk + f + 4);
      __align__(16) __hip_bfloat16 tmp[8];
      tmp[0] = __float2bfloat16(a0.x); tmp[1] = __float2bfloat16(a0.y);
      tmp[2] = __float2bfloat16(a0.z); tmp[3] = __float2bfloat16(a0.w);
      tmp[4] = __float2bfloat16(a1.x); tmp[5] = __float2bfloat16(a1.y);
      tmp[6] = __float2bfloat16(a1.z); tmp[7] = __float2bfloat16(a1.w);
      *(uint4*)(xbblk + f) = *(const uint4*)tmp;
    }
  }
}

// ---------------------------------------------------------------------------
// Kernel 2: bf16 MFMA GEMM, 256x256 tile, BK=64, 8-phase 2-buffer pipeline.
// 512 threads = 8 waves (wr in {0,1} n-dir x wc in 0..3 b-dir); per-wave
// output 128x64.  acc[mi][ni][r] = C'[n = n0 + wr*128 + mi*16 + quad*4 + r]
// [b = b0 + wc*64 + ni*16 + r16]; l = quad*4+r, o = n/16.
// LDS (128 KB): buffer u at u*64KB: A-half0 | A-half1 | B-half0 | B-half1,
// each 128 rows x 128 B.  Wave reads only A-half(wr) and B-half(wc>>1).
// ---------------------------------------------------------------------------
#define STAGE_H(ktt, h)                                                        \
  do {                                                                         \
    char* _d = smem + (((ktt) & 1) * 65536) + (h) * 16384 + t * 16;            \
    const __hip_bfloat16* _s = (((h) < 2) ? aG : bG) +                         \
        (long)((h) & 1) * 131072 + (long)(ktt) * 64 + hOff;                    \
    ASYNC_COPY16(_s, _d);                                                      \
    ASYNC_COPY16(_s + 65536, _d + 8192);                                       \
  } while (0)

#define RD_A(U, RH)                                                            \
  do {                                                                         \
    const char* _ab = smem + (U) * 65536 + wrOff + (RH) * 8192 + r16 * 128;    \
    a00 = *(const bf16x8*)(_ab + kx0);                                         \
    a01 = *(const bf16x8*)(_ab + kx1);                                         \
    a10 = *(const bf16x8*)(_ab + 2048 + kx0);                                  \
    a11 = *(const bf16x8*)(_ab + 2048 + kx1);                                  \
    a20 = *(const bf16x8*)(_ab + 4096 + kx0);                                  \
    a21 = *(const bf16x8*)(_ab + 4096 + kx1);                                  \
    a30 = *(const bf16x8*)(_ab + 6144 + kx0);                                  \
    a31 = *(const bf16x8*)(_ab + 6144 + kx1);                                  \
  } while (0)

#define RD_B0(U)                                                               \
  do {                                                                         \
    const char* _bb = smem + (U) * 65536 + 32768 + bOff + r16 * 128;           \
    b00 = *(const bf16x8*)(_bb + kx0);                                         \
    b01 = *(const bf16x8*)(_bb + kx1);                                         \
    b10 = *(const bf16x8*)(_bb + 2048 + kx0);                                  \
    b11 = *(const bf16x8*)(_bb + 2048 + kx1);                                  \
  } while (0)

#define RD_B1(U)                                                               \
  do {                                                                         \
    const char* _bb = smem + (U) * 65536 + 32768 + bOff + r16 * 128;           \
    b20 = *(const bf16x8*)(_bb + 4096 + kx0);                                  \
    b21 = *(const bf16x8*)(_bb + 4096 + kx1);                                  \
    b30 = *(const bf16x8*)(_bb + 6144 + kx0);                                  \
    b31 = *(const bf16x8*)(_bb + 6144 + kx1);                                  \
  } while (0)

// 16 MFMA = quadrant (rowhalf RH, colhalf 0): 8 independent ks0 then 8 ks1.
#define MM_C0(RH)                                                              \
    acc[(RH)*4+0][0] = __builtin_amdgcn_mfma_f32_16x16x32_bf16(a00, b00, acc[(RH)*4+0][0], 0, 0, 0); \
    acc[(RH)*4+0][1] = __builtin_amdgcn_mfma_f32_16x16x32_bf16(a00, b10, acc[(RH)*4+0][1], 0, 0, 0); \
    acc[(RH)*4+1][0] = __builtin_amdgcn_mfma_f32_16x16x32_bf16(a10, b00, acc[(RH)*4+1][0], 0, 0, 0); \
    acc[(RH)*4+1][1] = __builtin_amdgcn_mfma_f32_16x16x32_bf16(a10, b10, acc[(RH)*4+1][1], 0, 0, 0); \
    acc[(RH)*4+2][0] = __builtin_amdgcn_mfma_f32_16x16x32_bf16(a20, b00, acc[(RH)*4+2][0], 0, 0, 0); \
    acc[(RH)*4+2][1] = __builtin_amdgcn_mfma_f32_16x16x32_bf16(a20, b10, acc[(RH)*4+2][1], 0, 0, 0); \
    acc[(RH)*4+3][0] = __builtin_amdgcn_mfma_f32_16x16x32_bf16(a30, b00, acc[(RH)*4+3][0], 0, 0, 0); \
    acc[(RH)*4+3][1] = __builtin_amdgcn_mfma_f32_16x16x32_bf16(a30, b10, acc[(RH)*4+3][1], 0, 0, 0); \
    acc[(RH)*4+0][0] = __builtin_amdgcn_mfma_f32_16x16x32_bf16(a01, b01, acc[(RH)*4+0][0], 0, 0, 0); \
    acc[(RH)*4+0][1] = __builtin_amdgcn_mfma_f32_16x16x32_bf16(a01, b11, acc[(RH)*4+0][1], 0, 0, 0); \
    acc[(RH)*4+1][0] = __builtin_amdgcn_mfma_f32_16x16x32_bf16(a11, b01, acc[(RH)*4+1][0], 0, 0, 0); \
    acc[(RH)*4+1][1] = __builtin_amdgcn_mfma_f32_16x16x32_bf16(a11, b11, acc[(RH)*4+1][1], 0, 0, 0); \
    acc[(RH)*4+2][0] = __builtin_amdgcn_mfma_f32_16x16x32_bf16(a21, b01, acc[(RH)*4+2][0], 0, 0, 0); \
    acc[(RH)*4+2][1] = __builtin_amdgcn_mfma_f32_16x16x32_bf16(a21, b11, acc[(RH)*4+2][1], 0, 0, 0); \
    acc[(RH)*4+3][0] = __builtin_amdgcn_mfma_f32_16x16x32_bf16(a31, b01, acc[(RH)*4+3][0], 0, 0, 0); \
    acc[(RH)*4+3][1] = __builtin_amdgcn_mfma_f32_16x16x32_bf16(a31, b11, acc[(RH)*4+3][1], 0, 0, 0);

// quadrant (RH, colhalf 1)
#define MM_C1(RH)                                                              \
    acc[(RH)*4+0][2] = __builtin_amdgcn_mfma_f32_16x16x32_bf16(a00, b20, acc[(RH)*4+0][2], 0, 0, 0); \
    acc[(RH)*4+0][3] = __builtin_amdgcn_mfma_f32_16x16x32_bf16(a00, b30, acc[(RH)*4+0][3], 0, 0, 0); \
    acc[(RH)*4+1][2] = __builtin_amdgcn_mfma_f32_16x16x32_bf16(a10, b20, acc[(RH)*4+1][2], 0, 0, 0); \
    acc[(RH)*4+1][3] = __builtin_amdgcn_mfma_f32_16x16x32_bf16(a10, b30, acc[(RH)*4+1][3], 0, 0, 0); \
    acc[(RH)*4+2][2] = __builtin_amdgcn_mfma_f32_16x16x32_bf16(a20, b20, acc[(RH)*4+2][2], 0, 0, 0); \
    acc[(RH)*4+2][3] = __builtin_amdgcn_mfma_f32_16x16x32_bf16(a20, b30, acc[(RH)*4+2][3], 0, 0, 0); \
    acc[(RH)*4+3][2] = __builtin_amdgcn_mfma_f32_16x16x32_bf16(a30, b20, acc[(RH)*4+3][2], 0, 0, 0); \
    acc[(RH)*4+3][3] = __builtin_amdgcn_mfma_f32_16x16x32_bf16(a30, b30, acc[(RH)*4+3][3], 0, 0, 0); \
    acc[(RH)*4+0][2] = __builtin_amdgcn_mfma_f32_16x16x32_bf16(a01, b21, acc[(RH)*4+0][2], 0, 0, 0); \
    acc[(RH)*4+0][3] = __builtin_amdgcn_mfma_f32_16x16x32_bf16(a01, b31, acc[(RH)*4+0][3], 0, 0, 0); \
    acc[(RH)*4+1][2] = __builtin_amdgcn_mfma_f32_16x16x32_bf16(a11, b21, acc[(RH)*4+1][2], 0, 0, 0); \
    acc[(RH)*4+1][3] = __builtin_amdgcn_mfma_f32_16x16x32_bf16(a11, b31, acc[(RH)*4+1][3], 0, 0, 0); \
    acc[(RH)*4+2][2] = __builtin_amdgcn_mfma_f32_16x16x32_bf16(a21, b21, acc[(RH)*4+2][2], 0, 0, 0); \
    acc[(RH)*4+2][3] = __builtin_amdgcn_mfma_f32_16x16x32_bf16(a21, b31, acc[(RH)*4+2][3], 0, 0, 0); \
    acc[(RH)*4+3][2] = __builtin_amdgcn_mfma_f32_16x16x32_bf16(a31, b21, acc[(RH)*4+3][2], 0, 0, 0); \
    acc[(RH)*4+3][3] = __builtin_amdgcn_mfma_f32_16x16x32_bf16(a31, b31, acc[(RH)*4+3][3], 0, 0, 0);

#define PHASE_SYNC                                                             \
    __builtin_amdgcn_s_barrier();                                              \
    asm volatile("s_waitcnt lgkmcnt(0)" ::: "memory");                         \
    __builtin_amdgcn_sched_barrier(0);

// One K-tile = 4 phases.  Reads/phase: 12, 4, 8, 0.  Stage one half-tile of
// kt+1 per phase; boundary vmcnt(0)+barrier at P3 publishes kt+1's buffer.
#define KTILE(kt, U, DOSTAGE, DOVM)                                            \
  do {                                                                         \
    /* P0: quadrant (rh0, ch0) */                                              \
    RD_A(U, 0);                                                                \
    RD_B0(U);                                                                  \
    if (DOSTAGE) STAGE_H((kt) + 1, 0);                                         \
    PHASE_SYNC;                                                                \
    __builtin_amdgcn_s_setprio(1);                                             \
    MM_C0(0);                                                                  \
    __builtin_amdgcn_s_setprio(0);                                             \
    __builtin_amdgcn_s_barrier();                                              \
    /* P1: quadrant (rh0, ch1) — A regs reused */                              \
    RD_B1(U);                                                                  \
    if (DOSTAGE) STAGE_H((kt) + 1, 1);                                         \
    PHASE_SYNC;                                                                \
    __builtin_amdgcn_s_setprio(1);                                             \
    MM_C1(0);                                                                  \
    __builtin_amdgcn_s_setprio(0);                                             \
    __builtin_amdgcn_s_barrier();                                              \
    /* P2: quadrant (rh1, ch0) — B0 regs reused, A overwritten */              \
    RD_A(U, 1);                                                                \
    if (DOSTAGE) STAGE_H((kt) + 1, 2);                                         \
    PHASE_SYNC;                                                                \
    __builtin_amdgcn_s_setprio(1);                                             \
    MM_C0(1);                                                                  \
    __builtin_amdgcn_s_setprio(0);                                             \
    __builtin_amdgcn_s_barrier();                                              \
    /* P3: quadrant (rh1, ch1) — no reads; boundary vmcnt */                   \
    if (DOSTAGE) STAGE_H((kt) + 1, 3);                                         \
    __builtin_amdgcn_s_barrier();                                              \
    __builtin_amdgcn_s_setprio(1);                                             \
    MM_C1(1);                                                                  \
    __builtin_amdgcn_s_setprio(0);                                             \
    if (DOVM) { asm volatile("s_waitcnt vmcnt(0)" ::: "memory"); }             \
    __builtin_amdgcn_s_barrier();                                              \
  } while (0)

__global__ __launch_bounds__(512, 2) void gemm_kernel(
    const __hip_bfloat16* __restrict__ Xb,  // [BATCH, KK]
    const __hip_bfloat16* __restrict__ W,   // [NN, KK], row n = o*16+l
    const float* __restrict__ g,            // [BATCH, NLEAF]
    const float* __restrict__ pb,           // [OUT_F, NLEAF]
    float* __restrict__ out) {              // [BATCH, OUT_F]
  extern __shared__ __align__(16) char smem[];  // 2 buffers x 64 KB

  const int t    = threadIdx.x;
  const int lane = t & 63;
  const int w    = t >> 6;
  const int quad = lane >> 4;
  const int r16  = lane & 15;
  const int wr   = w >> 2;   // 0..1: A rows wr*128 (= A-half index)
  const int wc   = w & 3;    // 0..3: B rows (b-dir) wc*64

  // T1: XCD-chunked bijective block swizzle (nwg = 16*64 = 1024, %8 == 0).
  // HW dispatch index lin round-robins XCDs; swz gives each XCD a contiguous
  // 128-tile range = 8 full A-panel rows (8 x 512KB = 4MB = one L2).
  const int lin = blockIdx.y * gridDim.x + blockIdx.x;   // 0..1023
  const int swz = (lin & 7) * 128 + (lin >> 3);
  const int b0_ = (swz & 15) * BN;
  const int n0  = (swz >> 4) * BM;

  const __hip_bfloat16* aG = W  + (long)n0 * KK;
  const __hip_bfloat16* bG = Xb + (long)b0_ * KK;

  // staging: half-tile = 128 rows x 128 B = 1024 chunks of 16 B; thread t
  // handles chunks t and t+512.  LDS linear; global K-slot = (c&7)^(row&7).
  const long hOff = (long)(t >> 3) * 1024 + (long)(((t & 7) ^ ((t >> 3) & 7)) * 8);

  // fragment read constants: slot byte = ((ks*4+quad)^(r16&7))*16
  const int kx0 = (quad ^ (r16 & 7)) * 16;
  const int kx1 = kx0 ^ 64;
  const int wrOff = wr * 16384;
  const int bOff  = (wc >> 1) * 16384 + (wc & 1) * 8192;

  f32x4 acc[8][4] = {};
  bf16x8 a00, a01, a10, a11, a20, a21, a30, a31;
  bf16x8 b00, b01, b10, b11, b20, b21, b30, b31;

  // Prologue: stage K-tile 0's 4 half-tiles into buffer 0; drain; publish.
  STAGE_H(0, 0); STAGE_H(0, 1); STAGE_H(0, 2); STAGE_H(0, 3);
  asm volatile("s_waitcnt vmcnt(0)" ::: "memory");
  __builtin_amdgcn_s_barrier();

  for (int kt = 0; kt < NKT - 2; kt += 2) {
    KTILE(kt, 0, 1, 1);
    KTILE(kt + 1, 1, 1, 1);
  }
  KTILE(NKT - 2, 0, 1, 1);
  KTILE(NKT - 1, 1, 0, 0);

  // ---- stage g (transposed, padded) and pb into the (dead) buffer-0 LDS ----
  // All frag reads drained by per-phase lgkmcnt(0) before the final barrier.
  float* gs  = (float*)smem;                       // [16][GS_PAD]
  float* pbs = (float*)(smem + 16 * GS_PAD * 4);   // [256]
#pragma unroll
  for (int j = 0; j < 8; ++j) {
    const int f = t + 512 * j;                     // 0..4095
    gs[(f & 15) * GS_PAD + (f >> 4)] = g[b0_ * NLEAF + f];
  }
  if (t < 256) pbs[t] = pb[(n0 >> 4) * NLEAF + t]; // o0 = n0/16; pb flat [o,l]
  __syncthreads();

  // ---- fused gated-reduction epilogue ----
  const int oBase = (n0 >> 4) + wr * 8;            // 8 consecutive o's (mi)
#pragma unroll
  for (int ni = 0; ni < 4; ++ni) {
    const int bl = wc * 64 + ni * 16 + r16;
    float gv[4];
#pragma unroll
    for (int r = 0; r < 4; ++r) gv[r] = gs[(quad * 4 + r) * GS_PAD + bl];
    float rv[8];
#pragma unroll
    for (int mi = 0; mi < 8; ++mi) {
      float v = 0.f;
#pragma unroll
      for (int r = 0; r < 4; ++r)
        v = fmaf(acc[mi][ni][r] + pbs[(wr * 8 + mi) * NLEAF + quad * 4 + r],
                 gv[r], v);
      v += __shfl_xor(v, 16);
      v += __shfl_xor(v, 32);                      // sum over quads -> sum_l
      rv[mi] = v;
    }
    if (quad == 0) {
      *(float4*)(out + (long)(b0_ + bl) * OUT_F + oBase) =
          make_float4(rv[0], rv[1], rv[2], rv[3]);
      *(float4*)(out + (long)(b0_ + bl) * OUT_F + oBase + 4) =
          make_float4(rv[4], rv[5], rv[6], rv[7]);
    }
  }
}

// ---------------------------------------------------------------------------
// Fallback (ws too small for packed buffers): slow but correct fp32 path.
// ---------------------------------------------------------------------------
__global__ __launch_bounds__(256) void gate_kernel_fb(
    const float* __restrict__ x, const float* __restrict__ gw,
    const float* __restrict__ gb, float* __restrict__ g) {
  const int lane = threadIdx.x & 63;
  const int wv   = threadIdx.x >> 6;
  const int b    = blockIdx.x * 4 + wv;
  const int i4   = lane >> 4;
  const int l    = lane & 15;
  const float* xrow = x + (size_t)b * IN_F;
  float acc = 0.f;
  for (int k = 0; k < IN_F / 4; ++k)
    acc = fmaf(xrow[k * 4 + i4], gw[k * 64 + lane], acc);
  acc += __shfl_xor(acc, 16);
  acc += __shfl_xor(acc, 32);
  float logit = acc + gb[l];
  float m = logit;
  for (int off = 8; off > 0; off >>= 1) m = fmaxf(m, __shfl_xor(m, off));
  float e = __expf(logit - m);
  float s = e;
  for (int off = 8; off > 0; off >>= 1) s += __shfl_xor(s, off);
  if (lane < NLEAF) g[b * NLEAF + l] = e / s;
}

__global__ __launch_bounds__(256) void fallback_kernel(
    const float* __restrict__ x, const float* __restrict__ pw,
    const float* __restrict__ pb, const float* __restrict__ g,
    float* __restrict__ out) {
  const int b = blockIdx.x;
  __shared__ float xs[IN_F];
  __shared__ float gsl[NLEAF];
  const int t = threadIdx.x;
  for (int j = t; j < IN_F; j += 256) xs[j] = x[(long)b * IN_F + j];
  if (t < NLEAF) gsl[t] = g[b * NLEAF + t];
  __syncthreads();
  for (int o = t; o < OUT_F; o += 256) {
    const float* pwo = pw + (long)o * (IN_F * NLEAF);
    float acc = 0.f;
    for (int i = 0; i < IN_F; ++i) {
      const float xv = xs[i];
      float wsum = 0.f;
#pragma unroll
      for (int l = 0; l < NLEAF; ++l) wsum += gsl[l] * pwo[i * NLEAF + l];
      acc += xv * wsum;
    }
    float bias = 0.f;
#pragma unroll
    for (int l = 0; l < NLEAF; ++l) bias += gsl[l] * pb[o * NLEAF + l];
    out[(long)b * OUT_F + o] = acc + bias;
  }
}

extern "C" void kernel_launch(void* const* d_in, const int* in_sizes, int n_in,
                              void* d_out, int out_size, void* d_ws, size_t ws_size,
                              hipStream_t stream) {
  const float* x  = (const float*)d_in[0];  // [4096,1024]
  const float* gw = (const float*)d_in[1];  // [1024,16]
  const float* gb = (const float*)d_in[2];  // [16]
  const float* pw = (const float*)d_in[3];  // [1024,1024,16]
  const float* pb = (const float*)d_in[4];  // [1024,16]
  float* out = (float*)d_out;               // [4096,1024]

  const size_t w_bytes  = (size_t)NN * KK * sizeof(__hip_bfloat16);    // 33.6 MB
  const size_t xb_bytes = (size_t)BATCH * KK * sizeof(__hip_bfloat16); //  8.4 MB
  const size_t g_bytes  = (size_t)BATCH * NLEAF * sizeof(float);       //  0.26 MB

  if (ws_size >= w_bytes + xb_bytes + g_bytes) {
    __hip_bfloat16* W  = (__hip_bfloat16*)d_ws;
    __hip_bfloat16* xb = (__hip_bfloat16*)((char*)d_ws + w_bytes);
    float*          g  = (float*)((char*)d_ws + w_bytes + xb_bytes);

    static int attr_done = 0;
    if (!attr_done) {
      // 128 KB dynamic LDS (> 64 KB default cap); gfx950 has 160 KB/CU.
      (void)hipFuncSetAttribute((const void*)gemm_kernel,
                                hipFuncAttributeMaxDynamicSharedMemorySize,
                                131072);
      attr_done = 1;
    }

    prep_kernel<<<OUT_F + BATCH / 4, 256, 0, stream>>>(x, gw, gb, pw, g, xb, W);
    gemm_kernel<<<dim3(BATCH / BN, NN / BM), 512, 131072, stream>>>(
        xb, W, g, pb, out);
  } else {
    float* g = (float*)d_ws;  // needs only 256 KB
    gate_kernel_fb<<<BATCH / 4, 256, 0, stream>>>(x, gw, gb, g);
    fallback_kernel<<<BATCH, 256, 0, stream>>>(x, pw, pb, g, out);
  }
}